// Round 7
// baseline (3092.805 us; speedup 1.0000x reference)
//
#include <hip/hip_runtime.h>
#include <hip/hip_bf16.h>

// GCN: 3x GCNConv(H=64) + global mean pool + linear head.
// Round 6 -> 7: edge-parallel chunked gather. CSR reordered chunk-major
// (bin = c*N + v) so each (block,chunk) phase is one contiguous edge range;
// dst-local index packed into the csr word ((vi<<17)|u, needs N<=131072, NB=64).
// Waves stream edges (coalesced read + shfl broadcast, 8 loads in flight) and
// scatter via LDS ds_add_f32 (no dependent chain, no per-segment overhead).

#define WS_ALIGN(x) (((x) + 255) & ~size_t(255))
#define NCHUNK 16
#define NB 64          // dst rows per gather block (power of 2: vi = v & 63)
#define USH 17
#define UMASK 0x1FFFF

// zero bin counts/cursors (n16), degi=1 (self-loop), pool accumulators
__global__ __launch_bounds__(256) void k_init0(int n16, int n, int g, int* cnt,
                                               int* cursor, int* degi,
                                               float* gsum, float* gcnt) {
    int i = blockIdx.x * blockDim.x + threadIdx.x;
    if (i < n16) { cnt[i] = 0; cursor[i] = 0; }
    if (i < n) degi[i] = 1;
    if (i < g) { gsum[i] = 0.f; gcnt[i] = 0.f; }
}

// count per (chunk, dst) bin, chunk-major; also in-degree
__global__ __launch_bounds__(256) void k_cnt(int e, int n, int sc,
                                             const int* __restrict__ src,
                                             const int* __restrict__ dst,
                                             int* __restrict__ cnt,
                                             int* __restrict__ degi) {
    int i = blockIdx.x * blockDim.x + threadIdx.x;
    if (i >= e) return;
    int c = src[i] / sc;
    int v = dst[i];
    atomicAdd(&cnt[c * n + v], 1);
    atomicAdd(&degi[v], 1);
}

// scan1: 2048-elem tiles, 8 per thread; in-place capable
__global__ __launch_bounds__(256) void k_scan1(int n, const int* __restrict__ in,
                                               int* __restrict__ outx,
                                               int* __restrict__ psum) {
    __shared__ int sd[256];
    int tid = threadIdx.x;
    int i0 = blockIdx.x * 2048 + tid * 8;
    int a[8]; int tsum = 0;
#pragma unroll
    for (int q = 0; q < 8; ++q) { a[q] = (i0 + q < n) ? in[i0 + q] : 0; tsum += a[q]; }
    sd[tid] = tsum;
    __syncthreads();
    for (int off = 1; off < 256; off <<= 1) {
        int v = (tid >= off) ? sd[tid - off] : 0;
        __syncthreads();
        sd[tid] += v;
        __syncthreads();
    }
    int excl = sd[tid] - tsum;
#pragma unroll
    for (int q = 0; q < 8; ++q) { if (i0 + q < n) outx[i0 + q] = excl; excl += a[q]; }
    if (tid == 255) psum[blockIdx.x] = sd[255];
}

__global__ __launch_bounds__(256) void k_scan2(int nchunks, int* __restrict__ psum) {
    __shared__ int sd[256];
    int tid = threadIdx.x;
    int i0 = tid * 4;
    int a = (i0 + 0 < nchunks) ? psum[i0 + 0] : 0;
    int b = (i0 + 1 < nchunks) ? psum[i0 + 1] : 0;
    int c = (i0 + 2 < nchunks) ? psum[i0 + 2] : 0;
    int d = (i0 + 3 < nchunks) ? psum[i0 + 3] : 0;
    int tsum = a + b + c + d;
    sd[tid] = tsum;
    __syncthreads();
    for (int off = 1; off < 256; off <<= 1) {
        int v = (tid >= off) ? sd[tid - off] : 0;
        __syncthreads();
        sd[tid] += v;
        __syncthreads();
    }
    int excl = sd[tid] - tsum;
    if (i0 + 0 < nchunks) psum[i0 + 0] = excl;
    if (i0 + 1 < nchunks) psum[i0 + 1] = excl + a;
    if (i0 + 2 < nchunks) psum[i0 + 2] = excl + a + b;
    if (i0 + 3 < nchunks) psum[i0 + 3] = excl + a + b + c;
}

__global__ __launch_bounds__(256) void k_scan3(int n, int e, int* __restrict__ outx,
                                               const int* __restrict__ psum) {
    int i = blockIdx.x * blockDim.x + threadIdx.x;
    if (i < n) outx[i] += psum[i >> 11];
    if (i == n) outx[n] = e;
}

// dinv = 1/sqrt(deg); xs = x*dinv
__global__ __launch_bounds__(256) void k_dinv(int n, const int* __restrict__ degi,
                                              const float* __restrict__ x,
                                              float* __restrict__ dinv,
                                              float* __restrict__ xs) {
    int i = blockIdx.x * blockDim.x + threadIdx.x;
    if (i >= n) return;
    float di = 1.0f / sqrtf((float)degi[i]);
    dinv[i] = di;
    xs[i] = x[i] * di;
}

// scatter into chunk-major CSR; pack (vi<<17)|u
__global__ __launch_bounds__(256) void k_scatter(int e, int n, int sc,
                                                 const int* __restrict__ src,
                                                 const int* __restrict__ dst,
                                                 const int* __restrict__ starts,
                                                 int* __restrict__ cursor,
                                                 int* __restrict__ csrP) {
    int i = blockIdx.x * blockDim.x + threadIdx.x;
    if (i >= e) return;
    int u = src[i];
    int v = dst[i];
    int bin = (u / sc) * n + v;
    int pos = starts[bin] + atomicAdd(&cursor[bin], 1);
    csrP[pos] = ((v & (NB - 1)) << USH) | u;
}

// layer 1 (rank-1) edge-parallel: sL[vi] += xs[u] over 16 chunk phases,
// then transform the row: hs1 = relu(((sL+xs[v])*dinv)*w1 + b1)*dinv
__global__ __launch_bounds__(256, 8) void k_layer1_g(int n, const int* __restrict__ starts,
                                                     const int* __restrict__ csrP,
                                                     const float* __restrict__ xs,
                                                     const float* __restrict__ dinv,
                                                     const float* __restrict__ w1,
                                                     const float* __restrict__ b1,
                                                     float* __restrict__ hs_out) {
    __shared__ float sL[NB];
    int tid = threadIdx.x;
    int v0 = blockIdx.x * NB;
    int nb = n - v0; if (nb > NB) nb = NB;
    if (nb <= 0) return;
    if (tid < NB) sL[tid] = 0.f;
    __syncthreads();
    for (int c = 0; c < NCHUNK; ++c) {
        int e0 = starts[c * n + v0];
        int e1 = starts[c * n + v0 + nb];
        for (int k = e0 + tid; k < e1; k += 256) {
            int pk = csrP[k];
            atomicAdd(&sL[pk >> USH], xs[pk & UMASK]);
        }
        __syncthreads();
    }
    int r = tid >> 6, lane = tid & 63;
    float w1r = w1[lane], b1r = b1[lane];
    for (int vi = r; vi < nb; vi += 4) {
        int v = v0 + vi;
        float dv = dinv[v];
        float s = (sL[vi] + xs[v]) * dv;
        hs_out[(size_t)v * 64 + lane] = fmaxf(s * w1r + b1r, 0.f) * dv;
    }
}

// edge-parallel chunked gather: block owns NB dst rows in LDS; per chunk the
// block's edges are one contiguous range; waves stream 64 edges per round
// (coalesced packed read + shfl broadcast), ds_add_f32 scatter into accL.
__global__ __launch_bounds__(256, 8) void k_gather_e(int n, const int* __restrict__ starts,
                                                     const int* __restrict__ csrP,
                                                     const float* __restrict__ hs_in,
                                                     const float* __restrict__ dinv,
                                                     float* __restrict__ agg) {
    __shared__ float accL[NB * 64];
    int tid = threadIdx.x, r = tid >> 6, lane = tid & 63;
    int v0 = blockIdx.x * NB;
    int nb = n - v0; if (nb > NB) nb = NB;
    if (nb <= 0) return;
    for (int vi = r; vi < nb; vi += 4)
        accL[vi * 64 + lane] = hs_in[(size_t)(v0 + vi) * 64 + lane];   // self-loop
    __syncthreads();
    for (int c = 0; c < NCHUNK; ++c) {
        int e0 = starts[c * n + v0];
        int e1 = starts[c * n + v0 + nb];
        for (int base = e0 + r * 64; base < e1; base += 256) {
            int k = base + lane;
            int pk = (k < e1) ? csrP[k] : 0;
            int m = e1 - base; if (m > 64) m = 64;
            int t = 0;
            for (; t + 8 <= m; t += 8) {
                int p0 = __shfl(pk, t, 64),     p1 = __shfl(pk, t + 1, 64);
                int p2 = __shfl(pk, t + 2, 64), p3 = __shfl(pk, t + 3, 64);
                int p4 = __shfl(pk, t + 4, 64), p5 = __shfl(pk, t + 5, 64);
                int p6 = __shfl(pk, t + 6, 64), p7 = __shfl(pk, t + 7, 64);
                float g0 = hs_in[(size_t)(p0 & UMASK) * 64 + lane];
                float g1 = hs_in[(size_t)(p1 & UMASK) * 64 + lane];
                float g2 = hs_in[(size_t)(p2 & UMASK) * 64 + lane];
                float g3 = hs_in[(size_t)(p3 & UMASK) * 64 + lane];
                float g4 = hs_in[(size_t)(p4 & UMASK) * 64 + lane];
                float g5 = hs_in[(size_t)(p5 & UMASK) * 64 + lane];
                float g6 = hs_in[(size_t)(p6 & UMASK) * 64 + lane];
                float g7 = hs_in[(size_t)(p7 & UMASK) * 64 + lane];
                atomicAdd(&accL[(p0 >> USH) * 64 + lane], g0);
                atomicAdd(&accL[(p1 >> USH) * 64 + lane], g1);
                atomicAdd(&accL[(p2 >> USH) * 64 + lane], g2);
                atomicAdd(&accL[(p3 >> USH) * 64 + lane], g3);
                atomicAdd(&accL[(p4 >> USH) * 64 + lane], g4);
                atomicAdd(&accL[(p5 >> USH) * 64 + lane], g5);
                atomicAdd(&accL[(p6 >> USH) * 64 + lane], g6);
                atomicAdd(&accL[(p7 >> USH) * 64 + lane], g7);
            }
            for (; t < m; ++t) {
                int p = __shfl(pk, t, 64);
                atomicAdd(&accL[(p >> USH) * 64 + lane],
                          hs_in[(size_t)(p & UMASK) * 64 + lane]);
            }
        }
        __syncthreads();   // chunk phase alignment + ds_add visibility
    }
    for (int vi = r; vi < nb; vi += 4) {
        int v = v0 + vi;
        agg[(size_t)v * 64 + lane] = accL[vi * 64 + lane] * dinv[v];
    }
}

// persistent wave-per-node GEMM: hs_out = relu(agg@w+b)*dinv
__global__ __launch_bounds__(256, 8) void k_gemm_mid(int n, const float* __restrict__ agg,
                                                     const float* __restrict__ w,
                                                     const float* __restrict__ b,
                                                     const float* __restrict__ dinv,
                                                     float* __restrict__ hs_out) {
    __shared__ float ws[64 * 64];
    __shared__ float rowl[4][64];
    int tid = threadIdx.x;
    for (int k = tid; k < 64 * 64; k += 256) ws[k] = w[k];
    __syncthreads();
    int r = tid >> 6, lane = tid & 63;
    float breg = b[lane];
    int wid = blockIdx.x * 4 + r;
    int stride = gridDim.x * 4;
    for (int v = wid; v < n; v += stride) {
        rowl[r][lane] = agg[(size_t)v * 64 + lane];
        float acc = breg;
#pragma unroll
        for (int k = 0; k < 64; ++k) acc += rowl[r][k] * ws[k * 64 + lane];
        hs_out[(size_t)v * 64 + lane] = fmaxf(acc, 0.f) * dinv[v];
    }
}

// persistent final GEMM: dots[v] = relu(agg@w3+b3) . fcw
__global__ __launch_bounds__(256, 8) void k_gemm_final(int n, const float* __restrict__ agg,
                                                       const float* __restrict__ w,
                                                       const float* __restrict__ b,
                                                       const float* __restrict__ fcw,
                                                       float* __restrict__ dots) {
    __shared__ float ws[64 * 64];
    __shared__ float rowl[4][64];
    int tid = threadIdx.x;
    for (int k = tid; k < 64 * 64; k += 256) ws[k] = w[k];
    __syncthreads();
    int r = tid >> 6, lane = tid & 63;
    float breg = b[lane];
    float freg = fcw[lane];
    int wid = blockIdx.x * 4 + r;
    int stride = gridDim.x * 4;
    for (int v = wid; v < n; v += stride) {
        rowl[r][lane] = agg[(size_t)v * 64 + lane];
        float acc = breg;
#pragma unroll
        for (int k = 0; k < 64; ++k) acc += rowl[r][k] * ws[k * 64 + lane];
        float val = fmaxf(acc, 0.f) * freg;
#pragma unroll
        for (int o = 32; o > 0; o >>= 1) val += __shfl_xor(val, o, 64);
        if (lane == 0) dots[v] = val;
    }
}

// pooled accumulation: LDS-binned segmented reduce over sorted batch.
__global__ __launch_bounds__(256) void k_pool(int n, const float* __restrict__ dots,
                                              const int* __restrict__ batch,
                                              float* __restrict__ gsum,
                                              float* __restrict__ gcnt) {
    __shared__ float ls[64], lc[64];
    __shared__ int gmin_s;
    int tid = threadIdx.x;
    int i0 = blockIdx.x * 1024;
    if (tid == 0) gmin_s = batch[i0];
    if (tid < 64) { ls[tid] = 0.f; lc[tid] = 0.f; }
    __syncthreads();
    int gmin = gmin_s;
#pragma unroll
    for (int c = 0; c < 4; ++c) {
        int i = i0 + c * 256 + tid;
        if (i < n) {
            int g = batch[i];
            float d = dots[i];
            int rr = g - gmin;
            if (rr < 64) {
                atomicAdd(&ls[rr], d);
                atomicAdd(&lc[rr], 1.f);
            } else {
                atomicAdd(&gsum[g], d);
                atomicAdd(&gcnt[g], 1.f);
            }
        }
    }
    __syncthreads();
    if (tid < 64 && lc[tid] != 0.f) {
        atomicAdd(&gsum[gmin + tid], ls[tid]);
        atomicAdd(&gcnt[gmin + tid], lc[tid]);
    }
}

__global__ __launch_bounds__(256) void k_out(int g, const float* __restrict__ gsum,
                                             const float* __restrict__ gcnt,
                                             const float* __restrict__ fcb,
                                             float* __restrict__ out) {
    int i = blockIdx.x * blockDim.x + threadIdx.x;
    if (i < g) out[i] = gsum[i] / fmaxf(gcnt[i], 1.f) + fcb[0];
}

extern "C" void kernel_launch(void* const* d_in, const int* in_sizes, int n_in,
                              void* d_out, int out_size, void* d_ws, size_t ws_size,
                              hipStream_t stream) {
    const float* x    = (const float*)d_in[0];
    const int*   ei   = (const int*)d_in[1];
    const int*   batch= (const int*)d_in[2];
    const float* w1   = (const float*)d_in[3];
    const float* b1   = (const float*)d_in[4];
    const float* w2   = (const float*)d_in[5];
    const float* b2   = (const float*)d_in[6];
    const float* w3   = (const float*)d_in[7];
    const float* b3   = (const float*)d_in[8];
    const float* fcw  = (const float*)d_in[9];
    const float* fcb  = (const float*)d_in[10];
    float* out = (float*)d_out;

    const int N = in_sizes[0];      // requires N <= 131072 for (vi<<17)|u packing
    const int E = in_sizes[1] / 2;
    const int G = out_size;
    const int H = 64;
    const int SC = (N + NCHUNK - 1) / NCHUNK;
    const int n16 = N * NCHUNK;

    const int* src = ei;
    const int* dst = ei + E;

    char* p = (char*)d_ws;
    int*   starts16 = (int*)p; p += WS_ALIGN(sizeof(int) * (size_t)(n16 + 1));
    int*   cursor16 = (int*)p; p += WS_ALIGN(sizeof(int) * (size_t)n16);
    int*   psum     = (int*)p; p += WS_ALIGN(sizeof(int) * 1024);
    int*   degi     = (int*)p; p += WS_ALIGN(sizeof(int) * N);
    int*   csrP     = (int*)p; p += WS_ALIGN(sizeof(int) * (size_t)E);
    float* dinv     = (float*)p; p += WS_ALIGN(sizeof(float) * N);
    float* xs       = (float*)p; p += WS_ALIGN(sizeof(float) * N);
    float* bufA     = (float*)p; p += WS_ALIGN(sizeof(float) * (size_t)N * H);
    float* bufB     = (float*)p; p += WS_ALIGN(sizeof(float) * (size_t)N * H);
    float* dots     = (float*)p; p += WS_ALIGN(sizeof(float) * N);
    float* gsum     = (float*)p; p += WS_ALIGN(sizeof(float) * G);
    float* gcnt     = (float*)p; p += WS_ALIGN(sizeof(float) * G);

    const int B = 256;
    int gridN    = (N + B - 1) / B;
    int gridE    = (E + B - 1) / B;
    int gridG    = (G + B - 1) / B;
    int grid16   = (n16 + B - 1) / B;
    int nscan    = (n16 + 2047) / 2048;
    int gridS3   = (n16 + 1 + B - 1) / B;
    int gridGa   = (N + NB - 1) / NB;          // 1563 blocks, all resident
    int gridPool = (N + 1023) / 1024;
    int gridPers = 2048;
    if (gridPers * 4 > N) gridPers = (N + 3) / 4;

    k_init0<<<grid16, B, 0, stream>>>(n16, N, G, starts16, cursor16, degi, gsum, gcnt);
    k_cnt<<<gridE, B, 0, stream>>>(E, N, SC, src, dst, starts16, degi);
    k_scan1<<<nscan, B, 0, stream>>>(n16, starts16, starts16, psum);
    k_scan2<<<1, B, 0, stream>>>(nscan, psum);
    k_scan3<<<gridS3, B, 0, stream>>>(n16, E, starts16, psum);
    k_dinv<<<gridN, B, 0, stream>>>(N, degi, x, dinv, xs);
    k_scatter<<<gridE, B, 0, stream>>>(E, N, SC, src, dst, starts16, cursor16, csrP);
    // layer 1 (rank-1, edge-parallel)
    k_layer1_g<<<gridGa, B, 0, stream>>>(N, starts16, csrP, xs, dinv, w1, b1, bufA);
    // layer 2
    k_gather_e<<<gridGa, B, 0, stream>>>(N, starts16, csrP, bufA, dinv, bufB);
    k_gemm_mid<<<gridPers, B, 0, stream>>>(N, bufB, w2, b2, dinv, bufA);
    // layer 3
    k_gather_e<<<gridGa, B, 0, stream>>>(N, starts16, csrP, bufA, dinv, bufB);
    k_gemm_final<<<gridPers, B, 0, stream>>>(N, bufB, w3, b3, fcw, dots);
    // pooling + head
    k_pool<<<gridPool, B, 0, stream>>>(N, dots, batch, gsum, gcnt);
    k_out<<<gridG, B, 0, stream>>>(G, gsum, gcnt, fcb, out);
}

// Round 8
// 845.874 us; speedup vs baseline: 3.6563x; 3.6563x over previous
//
#include <hip/hip_runtime.h>
#include <hip/hip_bf16.h>

// GCN: 3x GCNConv(H=64) + global mean pool + linear head.
// Round 7 -> 8: chunked gather done right. CSR binned [dst][chunk] (NCHUNK=8,
// 3.2MB slice fits per-XCD L2). Gather block owns 64 rows: all 513 segment
// bounds preloaded to LDS; per segment, uniform base via readfirstlane ->
// scalar s_load of 4 csr entries (no shfl chains), 4 hs loads in flight,
// register acc, one non-atomic LDS rmw (rows wave-exclusive). One barrier
// per chunk for grid phase alignment only.

#define WS_ALIGN(x) (((x) + 255) & ~size_t(255))
#define NCHUNK 8
#define NB 64          // dst rows per gather block
#define NROW_W (NB / 4)

// zero bin counts/cursors (n8), pool accumulators, csr pad
__global__ __launch_bounds__(256) void k_init0(int n8, int g, int e, int* cnt,
                                               int* cursor, int* csr,
                                               float* gsum, float* gcnt) {
    int i = blockIdx.x * blockDim.x + threadIdx.x;
    if (i < n8) { cnt[i] = 0; cursor[i] = 0; }
    if (i < g) { gsum[i] = 0.f; gcnt[i] = 0.f; }
    if (i < 4) csr[e + i] = 0;   // overread pad (4-wide edge groups)
}

// count per (dst, chunk) bin
__global__ __launch_bounds__(256) void k_cnt(int e, int sc,
                                             const int* __restrict__ src,
                                             const int* __restrict__ dst,
                                             int* __restrict__ cnt) {
    int i = blockIdx.x * blockDim.x + threadIdx.x;
    if (i >= e) return;
    atomicAdd(&cnt[dst[i] * NCHUNK + src[i] / sc], 1);
}

// scan1: 2048-elem tiles, 8 per thread; in-place capable
__global__ __launch_bounds__(256) void k_scan1(int n, const int* __restrict__ in,
                                               int* __restrict__ outx,
                                               int* __restrict__ psum) {
    __shared__ int sd[256];
    int tid = threadIdx.x;
    int i0 = blockIdx.x * 2048 + tid * 8;
    int a[8]; int tsum = 0;
#pragma unroll
    for (int q = 0; q < 8; ++q) { a[q] = (i0 + q < n) ? in[i0 + q] : 0; tsum += a[q]; }
    sd[tid] = tsum;
    __syncthreads();
    for (int off = 1; off < 256; off <<= 1) {
        int v = (tid >= off) ? sd[tid - off] : 0;
        __syncthreads();
        sd[tid] += v;
        __syncthreads();
    }
    int excl = sd[tid] - tsum;
#pragma unroll
    for (int q = 0; q < 8; ++q) { if (i0 + q < n) outx[i0 + q] = excl; excl += a[q]; }
    if (tid == 255) psum[blockIdx.x] = sd[255];
}

__global__ __launch_bounds__(256) void k_scan2(int nchunks, int* __restrict__ psum) {
    __shared__ int sd[256];
    int tid = threadIdx.x;
    int i0 = tid * 4;
    int a = (i0 + 0 < nchunks) ? psum[i0 + 0] : 0;
    int b = (i0 + 1 < nchunks) ? psum[i0 + 1] : 0;
    int c = (i0 + 2 < nchunks) ? psum[i0 + 2] : 0;
    int d = (i0 + 3 < nchunks) ? psum[i0 + 3] : 0;
    int tsum = a + b + c + d;
    sd[tid] = tsum;
    __syncthreads();
    for (int off = 1; off < 256; off <<= 1) {
        int v = (tid >= off) ? sd[tid - off] : 0;
        __syncthreads();
        sd[tid] += v;
        __syncthreads();
    }
    int excl = sd[tid] - tsum;
    if (i0 + 0 < nchunks) psum[i0 + 0] = excl;
    if (i0 + 1 < nchunks) psum[i0 + 1] = excl + a;
    if (i0 + 2 < nchunks) psum[i0 + 2] = excl + a + b;
    if (i0 + 3 < nchunks) psum[i0 + 3] = excl + a + b + c;
}

__global__ __launch_bounds__(256) void k_scan3(int n, int e, int* __restrict__ outx,
                                               const int* __restrict__ psum) {
    int i = blockIdx.x * blockDim.x + threadIdx.x;
    if (i < n) outx[i] += psum[i >> 11];
    if (i == n) outx[n] = e;
}

// dinv from per-row bin range (+1 self-loop); xs = x*dinv
__global__ __launch_bounds__(256) void k_dinv(int n, const int* __restrict__ starts,
                                              const float* __restrict__ x,
                                              float* __restrict__ dinv,
                                              float* __restrict__ xs) {
    int i = blockIdx.x * blockDim.x + threadIdx.x;
    if (i >= n) return;
    int deg = starts[(i + 1) * NCHUNK] - starts[i * NCHUNK] + 1;
    float di = 1.0f / sqrtf((float)deg);
    dinv[i] = di;
    xs[i] = x[i] * di;
}

__global__ __launch_bounds__(256) void k_scatter(int e, int sc,
                                                 const int* __restrict__ src,
                                                 const int* __restrict__ dst,
                                                 const int* __restrict__ starts,
                                                 int* __restrict__ cursor,
                                                 int* __restrict__ csr) {
    int i = blockIdx.x * blockDim.x + threadIdx.x;
    if (i >= e) return;
    int u = src[i];
    int bin = dst[i] * NCHUNK + u / sc;
    int pos = starts[bin] + atomicAdd(&cursor[bin], 1);
    csr[pos] = u;
}

// layer 1 fused (rank-1): row's full edge range is contiguous ([v*8, (v+1)*8))
__global__ __launch_bounds__(256, 8) void k_layer1(int n, const int* __restrict__ starts,
                                                   const int* __restrict__ csr,
                                                   const float* __restrict__ xs,
                                                   const float* __restrict__ dinv,
                                                   const float* __restrict__ w1,
                                                   const float* __restrict__ b1,
                                                   float* __restrict__ hs_out) {
    int tid = threadIdx.x;
    int r = tid >> 6, lane = tid & 63;
    float w1r = w1[lane], b1r = b1[lane];
    int wid = blockIdx.x * 4 + r;
    int stride = gridDim.x * 4;
    for (int v = wid; v < n; v += stride) {
        int s0 = starts[v * NCHUNK], s1 = starts[(v + 1) * NCHUNK];
        float acc = 0.f;
        for (int k = s0 + lane; k < s1; k += 64) acc += xs[csr[k]];
#pragma unroll
        for (int m = 32; m > 0; m >>= 1) acc += __shfl_xor(acc, m, 64);
        float dv = dinv[v];
        float s = (acc + xs[v]) * dv;
        hs_out[(size_t)v * 64 + lane] = fmaxf(s * w1r + b1r, 0.f) * dv;
    }
}

// chunked gather: block owns NB=64 rows; wave owns rows r mod 4 (exclusive ->
// non-atomic LDS acc). Bounds in LDS; uniform csr base -> scalar 4-edge loads.
__global__ __launch_bounds__(256, 8) void k_gather_c8(int n,
                                                      const int* __restrict__ starts,
                                                      const int* __restrict__ csr,
                                                      const float* __restrict__ hs_in,
                                                      const float* __restrict__ dinv,
                                                      float* __restrict__ agg) {
    __shared__ float accL[NB * 64];
    __shared__ int bndL[NB * NCHUNK + 1];
    int tid = threadIdx.x;
    int lane = tid & 63;
    int r = __builtin_amdgcn_readfirstlane(tid >> 6);   // wave id, uniform
    int v0 = blockIdx.x * NB;
    // bounds prologue: 513 consecutive ints
    int top = n * NCHUNK;
    for (int i = tid; i < NB * NCHUNK + 1; i += 256) {
        int gidx = v0 * NCHUNK + i;
        bndL[i] = starts[(gidx <= top) ? gidx : top];
    }
    // self-loop init (wave-owned rows)
    for (int vi = r; vi < NB; vi += 4) {
        int v = v0 + vi;
        if (v < n) accL[vi * 64 + lane] = hs_in[(size_t)v * 64 + lane];
    }
    __syncthreads();
    for (int c = 0; c < NCHUNK; ++c) {
        for (int q = 0; q < NROW_W; ++q) {
            int vi = q * 4 + r;
            int v = v0 + vi;
            if (v >= n) break;
            int s0 = __builtin_amdgcn_readfirstlane(bndL[vi * NCHUNK + c]);
            int s1 = __builtin_amdgcn_readfirstlane(bndL[vi * NCHUNK + c + 1]);
            if (s0 == s1) continue;
            float acc = 0.f;
            for (int base = s0; base < s1; base += 4) {
                int rem = s1 - base;
                int u0 = csr[base];          // uniform base -> s_load_dwordx4
                int u1 = csr[base + 1];
                int u2 = csr[base + 2];
                int u3 = csr[base + 3];
                u1 = (rem > 1) ? u1 : u0;    // tail: duplicate row (cache hit),
                u2 = (rem > 2) ? u2 : u0;    // add is gated below
                u3 = (rem > 3) ? u3 : u0;
                float g0 = hs_in[(size_t)u0 * 64 + lane];
                float g1 = hs_in[(size_t)u1 * 64 + lane];
                float g2 = hs_in[(size_t)u2 * 64 + lane];
                float g3 = hs_in[(size_t)u3 * 64 + lane];
                if (rem >= 4) {
                    acc += (g0 + g1) + (g2 + g3);
                } else {
                    acc += g0;
                    if (rem > 1) acc += g1;
                    if (rem > 2) acc += g2;
                }
            }
            accL[vi * 64 + lane] += acc;     // wave-exclusive row, no atomic
        }
        __syncthreads();   // chunk phase alignment across the grid
    }
    for (int vi = r; vi < NB; vi += 4) {
        int v = v0 + vi;
        if (v < n) agg[(size_t)v * 64 + lane] = accL[vi * 64 + lane] * dinv[v];
    }
}

// persistent wave-per-node GEMM: hs_out = relu(agg@w+b)*dinv
__global__ __launch_bounds__(256, 8) void k_gemm_mid(int n, const float* __restrict__ agg,
                                                     const float* __restrict__ w,
                                                     const float* __restrict__ b,
                                                     const float* __restrict__ dinv,
                                                     float* __restrict__ hs_out) {
    __shared__ float ws[64 * 64];
    __shared__ float rowl[4][64];
    int tid = threadIdx.x;
    for (int k = tid; k < 64 * 64; k += 256) ws[k] = w[k];
    __syncthreads();
    int r = tid >> 6, lane = tid & 63;
    float breg = b[lane];
    int wid = blockIdx.x * 4 + r;
    int stride = gridDim.x * 4;
    for (int v = wid; v < n; v += stride) {
        rowl[r][lane] = agg[(size_t)v * 64 + lane];
        float acc = breg;
#pragma unroll
        for (int k = 0; k < 64; ++k) acc += rowl[r][k] * ws[k * 64 + lane];
        hs_out[(size_t)v * 64 + lane] = fmaxf(acc, 0.f) * dinv[v];
    }
}

// persistent final GEMM: dots[v] = relu(agg@w3+b3) . fcw
__global__ __launch_bounds__(256, 8) void k_gemm_final(int n, const float* __restrict__ agg,
                                                       const float* __restrict__ w,
                                                       const float* __restrict__ b,
                                                       const float* __restrict__ fcw,
                                                       float* __restrict__ dots) {
    __shared__ float ws[64 * 64];
    __shared__ float rowl[4][64];
    int tid = threadIdx.x;
    for (int k = tid; k < 64 * 64; k += 256) ws[k] = w[k];
    __syncthreads();
    int r = tid >> 6, lane = tid & 63;
    float breg = b[lane];
    float freg = fcw[lane];
    int wid = blockIdx.x * 4 + r;
    int stride = gridDim.x * 4;
    for (int v = wid; v < n; v += stride) {
        rowl[r][lane] = agg[(size_t)v * 64 + lane];
        float acc = breg;
#pragma unroll
        for (int k = 0; k < 64; ++k) acc += rowl[r][k] * ws[k * 64 + lane];
        float val = fmaxf(acc, 0.f) * freg;
#pragma unroll
        for (int o = 32; o > 0; o >>= 1) val += __shfl_xor(val, o, 64);
        if (lane == 0) dots[v] = val;
    }
}

// pooled accumulation: LDS-binned segmented reduce over sorted batch.
__global__ __launch_bounds__(256) void k_pool(int n, const float* __restrict__ dots,
                                              const int* __restrict__ batch,
                                              float* __restrict__ gsum,
                                              float* __restrict__ gcnt) {
    __shared__ float ls[64], lc[64];
    __shared__ int gmin_s;
    int tid = threadIdx.x;
    int i0 = blockIdx.x * 1024;
    if (tid == 0) gmin_s = batch[i0];
    if (tid < 64) { ls[tid] = 0.f; lc[tid] = 0.f; }
    __syncthreads();
    int gmin = gmin_s;
#pragma unroll
    for (int c = 0; c < 4; ++c) {
        int i = i0 + c * 256 + tid;
        if (i < n) {
            int g = batch[i];
            float d = dots[i];
            int rr = g - gmin;
            if (rr < 64) {
                atomicAdd(&ls[rr], d);
                atomicAdd(&lc[rr], 1.f);
            } else {
                atomicAdd(&gsum[g], d);
                atomicAdd(&gcnt[g], 1.f);
            }
        }
    }
    __syncthreads();
    if (tid < 64 && lc[tid] != 0.f) {
        atomicAdd(&gsum[gmin + tid], ls[tid]);
        atomicAdd(&gcnt[gmin + tid], lc[tid]);
    }
}

__global__ __launch_bounds__(256) void k_out(int g, const float* __restrict__ gsum,
                                             const float* __restrict__ gcnt,
                                             const float* __restrict__ fcb,
                                             float* __restrict__ out) {
    int i = blockIdx.x * blockDim.x + threadIdx.x;
    if (i < g) out[i] = gsum[i] / fmaxf(gcnt[i], 1.f) + fcb[0];
}

extern "C" void kernel_launch(void* const* d_in, const int* in_sizes, int n_in,
                              void* d_out, int out_size, void* d_ws, size_t ws_size,
                              hipStream_t stream) {
    const float* x    = (const float*)d_in[0];
    const int*   ei   = (const int*)d_in[1];
    const int*   batch= (const int*)d_in[2];
    const float* w1   = (const float*)d_in[3];
    const float* b1   = (const float*)d_in[4];
    const float* w2   = (const float*)d_in[5];
    const float* b2   = (const float*)d_in[6];
    const float* w3   = (const float*)d_in[7];
    const float* b3   = (const float*)d_in[8];
    const float* fcw  = (const float*)d_in[9];
    const float* fcb  = (const float*)d_in[10];
    float* out = (float*)d_out;

    const int N = in_sizes[0];
    const int E = in_sizes[1] / 2;
    const int G = out_size;
    const int H = 64;
    const int SC = (N + NCHUNK - 1) / NCHUNK;   // src-chunk size (12500)
    const int n8 = N * NCHUNK;

    const int* src = ei;
    const int* dst = ei + E;

    char* p = (char*)d_ws;
    int*   starts8 = (int*)p; p += WS_ALIGN(sizeof(int) * (size_t)(n8 + 1));
    int*   cursor8 = (int*)p; p += WS_ALIGN(sizeof(int) * (size_t)n8);
    int*   psum    = (int*)p; p += WS_ALIGN(sizeof(int) * 1024);
    int*   csr     = (int*)p; p += WS_ALIGN(sizeof(int) * ((size_t)E + 4));
    float* dinv    = (float*)p; p += WS_ALIGN(sizeof(float) * N);
    float* xs      = (float*)p; p += WS_ALIGN(sizeof(float) * N);
    float* bufA    = (float*)p; p += WS_ALIGN(sizeof(float) * (size_t)N * H);
    float* bufB    = (float*)p; p += WS_ALIGN(sizeof(float) * (size_t)N * H);
    float* dots    = (float*)p; p += WS_ALIGN(sizeof(float) * N);
    float* gsum    = (float*)p; p += WS_ALIGN(sizeof(float) * G);
    float* gcnt    = (float*)p; p += WS_ALIGN(sizeof(float) * G);

    const int B = 256;
    int gridN    = (N + B - 1) / B;
    int gridE    = (E + B - 1) / B;
    int gridG    = (G + B - 1) / B;
    int grid8    = (n8 + B - 1) / B;
    int nscan    = (n8 + 2047) / 2048;          // 391 <= 1024
    int gridS3   = (n8 + 1 + B - 1) / B;
    int gridGa   = (N + NB - 1) / NB;           // 1563 blocks, all resident
    int gridPool = (N + 1023) / 1024;
    int gridPers = 2048;
    if (gridPers * 4 > N) gridPers = (N + 3) / 4;

    k_init0<<<grid8, B, 0, stream>>>(n8, G, E, starts8, cursor8, csr, gsum, gcnt);
    k_cnt<<<gridE, B, 0, stream>>>(E, SC, src, dst, starts8);
    k_scan1<<<nscan, B, 0, stream>>>(n8, starts8, starts8, psum);
    k_scan2<<<1, B, 0, stream>>>(nscan, psum);
    k_scan3<<<gridS3, B, 0, stream>>>(n8, E, starts8, psum);
    k_dinv<<<gridN, B, 0, stream>>>(N, starts8, x, dinv, xs);
    k_scatter<<<gridE, B, 0, stream>>>(E, SC, src, dst, starts8, cursor8, csr);
    // layer 1 (rank-1, fused; row range contiguous)
    k_layer1<<<gridPers, B, 0, stream>>>(N, starts8, csr, xs, dinv, w1, b1, bufA);
    // layer 2
    k_gather_c8<<<gridGa, B, 0, stream>>>(N, starts8, csr, bufA, dinv, bufB);
    k_gemm_mid<<<gridPers, B, 0, stream>>>(N, bufB, w2, b2, dinv, bufA);
    // layer 3
    k_gather_c8<<<gridGa, B, 0, stream>>>(N, starts8, csr, bufA, dinv, bufB);
    k_gemm_final<<<gridPers, B, 0, stream>>>(N, bufB, w3, b3, fcw, dots);
    // pooling + head
    k_pool<<<gridPool, B, 0, stream>>>(N, dots, batch, gsum, gcnt);
    k_out<<<gridG, B, 0, stream>>>(G, gsum, gcnt, fcb, out);
}

// Round 9
// 628.121 us; speedup vs baseline: 4.9239x; 1.3467x over previous
//
#include <hip/hip_runtime.h>
#include <hip/hip_bf16.h>

// GCN: 3x GCNConv(H=64) + global mean pool + linear head.
// Round 8 -> 9: gather+GEMM fusion with register accumulators.
// - CSR binned [dst][chunk], NCHUNK=8 (3.2MB src slice fits per-XCD L2).
// - Gather block owns NB=32 rows; wave owns 8 rows in acc[8] VGPRs (static
//   unroll). Row-PAIR processing: 2 scalar csr quads + 8 hs loads in flight.
// - Epilogue: inline GEMM (weights in LDS once/block, wave-local row slot),
//   removing the separate GEMM kernels and the agg round trip.

#define WS_ALIGN(x) (((x) + 255) & ~size_t(255))
#define NCHUNK 8
#define NB 32            // dst rows per gather block
#define RPW (NB / 4)     // rows per wave = 8

// zero bin counts/cursors (n8), pool accumulators, csr pad
__global__ __launch_bounds__(256) void k_init0(int n8, int g, int e, int* cnt,
                                               int* cursor, int* csr,
                                               float* gsum, float* gcnt) {
    int i = blockIdx.x * blockDim.x + threadIdx.x;
    if (i < n8) { cnt[i] = 0; cursor[i] = 0; }
    if (i < g) { gsum[i] = 0.f; gcnt[i] = 0.f; }
    if (i < 4) csr[e + i] = 0;   // overread pad (4-wide edge groups)
}

__global__ __launch_bounds__(256) void k_cnt(int e, int sc,
                                             const int* __restrict__ src,
                                             const int* __restrict__ dst,
                                             int* __restrict__ cnt) {
    int i = blockIdx.x * blockDim.x + threadIdx.x;
    if (i >= e) return;
    atomicAdd(&cnt[dst[i] * NCHUNK + src[i] / sc], 1);
}

// scan1: 2048-elem tiles, 8 per thread; in-place capable
__global__ __launch_bounds__(256) void k_scan1(int n, const int* __restrict__ in,
                                               int* __restrict__ outx,
                                               int* __restrict__ psum) {
    __shared__ int sd[256];
    int tid = threadIdx.x;
    int i0 = blockIdx.x * 2048 + tid * 8;
    int a[8]; int tsum = 0;
#pragma unroll
    for (int q = 0; q < 8; ++q) { a[q] = (i0 + q < n) ? in[i0 + q] : 0; tsum += a[q]; }
    sd[tid] = tsum;
    __syncthreads();
    for (int off = 1; off < 256; off <<= 1) {
        int v = (tid >= off) ? sd[tid - off] : 0;
        __syncthreads();
        sd[tid] += v;
        __syncthreads();
    }
    int excl = sd[tid] - tsum;
#pragma unroll
    for (int q = 0; q < 8; ++q) { if (i0 + q < n) outx[i0 + q] = excl; excl += a[q]; }
    if (tid == 255) psum[blockIdx.x] = sd[255];
}

__global__ __launch_bounds__(256) void k_scan2(int nchunks, int* __restrict__ psum) {
    __shared__ int sd[256];
    int tid = threadIdx.x;
    int i0 = tid * 4;
    int a = (i0 + 0 < nchunks) ? psum[i0 + 0] : 0;
    int b = (i0 + 1 < nchunks) ? psum[i0 + 1] : 0;
    int c = (i0 + 2 < nchunks) ? psum[i0 + 2] : 0;
    int d = (i0 + 3 < nchunks) ? psum[i0 + 3] : 0;
    int tsum = a + b + c + d;
    sd[tid] = tsum;
    __syncthreads();
    for (int off = 1; off < 256; off <<= 1) {
        int v = (tid >= off) ? sd[tid - off] : 0;
        __syncthreads();
        sd[tid] += v;
        __syncthreads();
    }
    int excl = sd[tid] - tsum;
    if (i0 + 0 < nchunks) psum[i0 + 0] = excl;
    if (i0 + 1 < nchunks) psum[i0 + 1] = excl + a;
    if (i0 + 2 < nchunks) psum[i0 + 2] = excl + a + b;
    if (i0 + 3 < nchunks) psum[i0 + 3] = excl + a + b + c;
}

__global__ __launch_bounds__(256) void k_scan3(int n, int e, int* __restrict__ outx,
                                               const int* __restrict__ psum) {
    int i = blockIdx.x * blockDim.x + threadIdx.x;
    if (i < n) outx[i] += psum[i >> 11];
    if (i == n) outx[n] = e;
}

// dinv from per-row bin range (+1 self-loop); xs = x*dinv
__global__ __launch_bounds__(256) void k_dinv(int n, const int* __restrict__ starts,
                                              const float* __restrict__ x,
                                              float* __restrict__ dinv,
                                              float* __restrict__ xs) {
    int i = blockIdx.x * blockDim.x + threadIdx.x;
    if (i >= n) return;
    int deg = starts[(i + 1) * NCHUNK] - starts[i * NCHUNK] + 1;
    float di = 1.0f / sqrtf((float)deg);
    dinv[i] = di;
    xs[i] = x[i] * di;
}

__global__ __launch_bounds__(256) void k_scatter(int e, int sc,
                                                 const int* __restrict__ src,
                                                 const int* __restrict__ dst,
                                                 const int* __restrict__ starts,
                                                 int* __restrict__ cursor,
                                                 int* __restrict__ csr) {
    int i = blockIdx.x * blockDim.x + threadIdx.x;
    if (i >= e) return;
    int u = src[i];
    int bin = dst[i] * NCHUNK + u / sc;
    int pos = starts[bin] + atomicAdd(&cursor[bin], 1);
    csr[pos] = u;
}

// layer 1 fused (rank-1): row's full edge range is contiguous
__global__ __launch_bounds__(256, 8) void k_layer1(int n, const int* __restrict__ starts,
                                                   const int* __restrict__ csr,
                                                   const float* __restrict__ xs,
                                                   const float* __restrict__ dinv,
                                                   const float* __restrict__ w1,
                                                   const float* __restrict__ b1,
                                                   float* __restrict__ hs_out) {
    int tid = threadIdx.x;
    int r = tid >> 6, lane = tid & 63;
    float w1r = w1[lane], b1r = b1[lane];
    int wid = blockIdx.x * 4 + r;
    int stride = gridDim.x * 4;
    for (int v = wid; v < n; v += stride) {
        int s0 = starts[v * NCHUNK], s1 = starts[(v + 1) * NCHUNK];
        float acc = 0.f;
        for (int k = s0 + lane; k < s1; k += 64) acc += xs[csr[k]];
#pragma unroll
        for (int m = 32; m > 0; m >>= 1) acc += __shfl_xor(acc, m, 64);
        float dv = dinv[v];
        float s = (acc + xs[v]) * dv;
        hs_out[(size_t)v * 64 + lane] = fmaxf(s * w1r + b1r, 0.f) * dv;
    }
}

// ---- fused chunked-gather + inline GEMM ----
// GATHER_CORE: fills acc[RPW] (register) with self + neighbor sums.
#define GATHER_CORE                                                            \
    __shared__ float ws[64 * 64];                                              \
    __shared__ float rowl[4][64];                                              \
    __shared__ int bndL[NB * NCHUNK + 1];                                      \
    int tid = threadIdx.x;                                                     \
    int lane = tid & 63;                                                       \
    int r = tid >> 6;                                                          \
    int v0 = blockIdx.x * NB;                                                  \
    for (int k = tid; k < 64 * 64; k += 256) ws[k] = w[k];                     \
    int top = n * NCHUNK;                                                      \
    for (int i = tid; i < NB * NCHUNK + 1; i += 256) {                         \
        int gidx = v0 * NCHUNK + i;                                            \
        bndL[i] = starts[(gidx <= top) ? gidx : top];                          \
    }                                                                          \
    float acc[RPW];                                                            \
    _Pragma("unroll")                                                          \
    for (int q = 0; q < RPW; ++q) {                                            \
        int v = v0 + q * 4 + r;                                                \
        acc[q] = (v < n) ? hs_in[(size_t)v * 64 + lane] : 0.f;                 \
    }                                                                          \
    __syncthreads();                                                           \
    for (int c = 0; c < NCHUNK; ++c) {                                         \
        _Pragma("unroll")                                                      \
        for (int t = 0; t < RPW / 2; ++t) {                                    \
            int viA = (2 * t) * 4 + r;                                         \
            int viB = (2 * t + 1) * 4 + r;                                     \
            int a0 = __builtin_amdgcn_readfirstlane(bndL[viA * NCHUNK + c]);   \
            int a1 = __builtin_amdgcn_readfirstlane(bndL[viA * NCHUNK + c + 1]);\
            int b0_ = __builtin_amdgcn_readfirstlane(bndL[viB * NCHUNK + c]);  \
            int b1_ = __builtin_amdgcn_readfirstlane(bndL[viB * NCHUNK + c + 1]);\
            int ba = a0, bb = b0_;                                             \
            while (ba < a1 || bb < b1_) {                                      \
                int remA = a1 - ba;                                            \
                int remB = b1_ - bb;                                           \
                int pa = (remA > 0) ? ba : bb;                                 \
                int pb = (remB > 0) ? bb : ba;                                 \
                int uA0 = csr[pa],     uA1 = csr[pa + 1];                      \
                int uA2 = csr[pa + 2], uA3 = csr[pa + 3];                      \
                int uB0 = csr[pb],     uB1 = csr[pb + 1];                      \
                int uB2 = csr[pb + 2], uB3 = csr[pb + 3];                      \
                float gA0 = hs_in[(size_t)uA0 * 64 + lane];                    \
                float gA1 = hs_in[(size_t)uA1 * 64 + lane];                    \
                float gA2 = hs_in[(size_t)uA2 * 64 + lane];                    \
                float gA3 = hs_in[(size_t)uA3 * 64 + lane];                    \
                float gB0 = hs_in[(size_t)uB0 * 64 + lane];                    \
                float gB1 = hs_in[(size_t)uB1 * 64 + lane];                    \
                float gB2 = hs_in[(size_t)uB2 * 64 + lane];                    \
                float gB3 = hs_in[(size_t)uB3 * 64 + lane];                    \
                if (remA >= 4) acc[2 * t] += (gA0 + gA1) + (gA2 + gA3);        \
                else if (remA > 0) {                                           \
                    acc[2 * t] += gA0;                                         \
                    if (remA > 1) acc[2 * t] += gA1;                           \
                    if (remA > 2) acc[2 * t] += gA2;                           \
                }                                                              \
                if (remB >= 4) acc[2 * t + 1] += (gB0 + gB1) + (gB2 + gB3);    \
                else if (remB > 0) {                                           \
                    acc[2 * t + 1] += gB0;                                     \
                    if (remB > 1) acc[2 * t + 1] += gB1;                       \
                    if (remB > 2) acc[2 * t + 1] += gB2;                       \
                }                                                              \
                ba += 4; bb += 4;                                              \
            }                                                                  \
        }                                                                      \
        __syncthreads();                                                       \
    }

// mid layer: hs_out = relu((acc*dinv) @ w + b) * dinv
__global__ __launch_bounds__(256, 8) void k_gg_mid(int n,
                                                   const int* __restrict__ starts,
                                                   const int* __restrict__ csr,
                                                   const float* __restrict__ hs_in,
                                                   const float* __restrict__ dinv,
                                                   const float* __restrict__ w,
                                                   const float* __restrict__ b,
                                                   float* __restrict__ hs_out) {
    GATHER_CORE
    float breg = b[lane];
#pragma unroll 1
    for (int q = 0; q < RPW; ++q) {
        int v = v0 + q * 4 + r;
        if (v >= n) continue;
        float dv = dinv[v];
        rowl[r][lane] = acc[q] * dv;
        float o = breg;
#pragma unroll
        for (int k = 0; k < 64; ++k) o += rowl[r][k] * ws[k * 64 + lane];
        hs_out[(size_t)v * 64 + lane] = fmaxf(o, 0.f) * dv;
    }
}

// final layer: dots[v] = relu((acc*dinv) @ w3 + b3) . fcw
__global__ __launch_bounds__(256, 8) void k_gg_final(int n,
                                                     const int* __restrict__ starts,
                                                     const int* __restrict__ csr,
                                                     const float* __restrict__ hs_in,
                                                     const float* __restrict__ dinv,
                                                     const float* __restrict__ w,
                                                     const float* __restrict__ b,
                                                     const float* __restrict__ fcw,
                                                     float* __restrict__ dots) {
    GATHER_CORE
    float breg = b[lane];
    float freg = fcw[lane];
#pragma unroll 1
    for (int q = 0; q < RPW; ++q) {
        int v = v0 + q * 4 + r;
        if (v >= n) continue;
        float dv = dinv[v];
        rowl[r][lane] = acc[q] * dv;
        float o = breg;
#pragma unroll
        for (int k = 0; k < 64; ++k) o += rowl[r][k] * ws[k * 64 + lane];
        float val = fmaxf(o, 0.f) * freg;
#pragma unroll
        for (int m = 32; m > 0; m >>= 1) val += __shfl_xor(val, m, 64);
        if (lane == 0) dots[v] = val;
    }
}

// pooled accumulation: LDS-binned segmented reduce over sorted batch.
__global__ __launch_bounds__(256) void k_pool(int n, const float* __restrict__ dots,
                                              const int* __restrict__ batch,
                                              float* __restrict__ gsum,
                                              float* __restrict__ gcnt) {
    __shared__ float ls[64], lc[64];
    __shared__ int gmin_s;
    int tid = threadIdx.x;
    int i0 = blockIdx.x * 1024;
    if (tid == 0) gmin_s = batch[i0];
    if (tid < 64) { ls[tid] = 0.f; lc[tid] = 0.f; }
    __syncthreads();
    int gmin = gmin_s;
#pragma unroll
    for (int c = 0; c < 4; ++c) {
        int i = i0 + c * 256 + tid;
        if (i < n) {
            int g = batch[i];
            float d = dots[i];
            int rr = g - gmin;
            if (rr < 64) {
                atomicAdd(&ls[rr], d);
                atomicAdd(&lc[rr], 1.f);
            } else {
                atomicAdd(&gsum[g], d);
                atomicAdd(&gcnt[g], 1.f);
            }
        }
    }
    __syncthreads();
    if (tid < 64 && lc[tid] != 0.f) {
        atomicAdd(&gsum[gmin + tid], ls[tid]);
        atomicAdd(&gcnt[gmin + tid], lc[tid]);
    }
}

__global__ __launch_bounds__(256) void k_out(int g, const float* __restrict__ gsum,
                                             const float* __restrict__ gcnt,
                                             const float* __restrict__ fcb,
                                             float* __restrict__ out) {
    int i = blockIdx.x * blockDim.x + threadIdx.x;
    if (i < g) out[i] = gsum[i] / fmaxf(gcnt[i], 1.f) + fcb[0];
}

extern "C" void kernel_launch(void* const* d_in, const int* in_sizes, int n_in,
                              void* d_out, int out_size, void* d_ws, size_t ws_size,
                              hipStream_t stream) {
    const float* x    = (const float*)d_in[0];
    const int*   ei   = (const int*)d_in[1];
    const int*   batch= (const int*)d_in[2];
    const float* w1   = (const float*)d_in[3];
    const float* b1   = (const float*)d_in[4];
    const float* w2   = (const float*)d_in[5];
    const float* b2   = (const float*)d_in[6];
    const float* w3   = (const float*)d_in[7];
    const float* b3   = (const float*)d_in[8];
    const float* fcw  = (const float*)d_in[9];
    const float* fcb  = (const float*)d_in[10];
    float* out = (float*)d_out;

    const int N = in_sizes[0];
    const int E = in_sizes[1] / 2;
    const int G = out_size;
    const int H = 64;
    const int SC = (N + NCHUNK - 1) / NCHUNK;   // src-chunk size (12500)
    const int n8 = N * NCHUNK;

    const int* src = ei;
    const int* dst = ei + E;

    char* p = (char*)d_ws;
    int*   starts8 = (int*)p; p += WS_ALIGN(sizeof(int) * (size_t)(n8 + 1));
    int*   cursor8 = (int*)p; p += WS_ALIGN(sizeof(int) * (size_t)n8);
    int*   psum    = (int*)p; p += WS_ALIGN(sizeof(int) * 1024);
    int*   csr     = (int*)p; p += WS_ALIGN(sizeof(int) * ((size_t)E + 4));
    float* dinv    = (float*)p; p += WS_ALIGN(sizeof(float) * N);
    float* xs      = (float*)p; p += WS_ALIGN(sizeof(float) * N);
    float* bufA    = (float*)p; p += WS_ALIGN(sizeof(float) * (size_t)N * H);
    float* bufB    = (float*)p; p += WS_ALIGN(sizeof(float) * (size_t)N * H);
    float* dots    = (float*)p; p += WS_ALIGN(sizeof(float) * N);
    float* gsum    = (float*)p; p += WS_ALIGN(sizeof(float) * G);
    float* gcnt    = (float*)p; p += WS_ALIGN(sizeof(float) * G);

    const int B = 256;
    int gridN    = (N + B - 1) / B;
    int gridE    = (E + B - 1) / B;
    int gridG    = (G + B - 1) / B;
    int grid8    = (n8 + B - 1) / B;
    int nscan    = (n8 + 2047) / 2048;
    int gridS3   = (n8 + 1 + B - 1) / B;
    int gridGa   = (N + NB - 1) / NB;           // 3125 gather blocks
    int gridPool = (N + 1023) / 1024;
    int gridPers = 2048;
    if (gridPers * 4 > N) gridPers = (N + 3) / 4;

    k_init0<<<grid8, B, 0, stream>>>(n8, G, E, starts8, cursor8, csr, gsum, gcnt);
    k_cnt<<<gridE, B, 0, stream>>>(E, SC, src, dst, starts8);
    k_scan1<<<nscan, B, 0, stream>>>(n8, starts8, starts8, psum);
    k_scan2<<<1, B, 0, stream>>>(nscan, psum);
    k_scan3<<<gridS3, B, 0, stream>>>(n8, E, starts8, psum);
    k_dinv<<<gridN, B, 0, stream>>>(N, starts8, x, dinv, xs);
    k_scatter<<<gridE, B, 0, stream>>>(E, SC, src, dst, starts8, cursor8, csr);
    // layer 1 (rank-1, fused)
    k_layer1<<<gridPers, B, 0, stream>>>(N, starts8, csr, xs, dinv, w1, b1, bufA);
    // layer 2: fused gather + GEMM(w2) -> bufB
    k_gg_mid<<<gridGa, B, 0, stream>>>(N, starts8, csr, bufA, dinv, w2, b2, bufB);
    // layer 3: fused gather + GEMM(w3) + fc dot -> dots
    k_gg_final<<<gridGa, B, 0, stream>>>(N, starts8, csr, bufB, dinv, w3, b3, fcw, dots);
    // pooling + head
    k_pool<<<gridPool, B, 0, stream>>>(N, dots, batch, gsum, gcnt);
    k_out<<<gridG, B, 0, stream>>>(G, gsum, gcnt, fcb, out);
}